// Round 2
// baseline (248.548 us; speedup 1.0000x reference)
//
#include <hip/hip_runtime.h>
#include <hip/hip_fp16.h>
#include <math.h>

// Problem constants (fixed by the reference setup_inputs)
constexpr int NH = 8;     // heads
constexpr int D = 32;     // head dim (c/nh)
constexpr int C = 256;    // channels
constexpr int H0 = 128;
constexpr int W0 = 128;
constexpr int PIX = H0 * W0;   // 16384
constexpr int LBLK = 4096;     // (H0/2)*(W0/2)
constexpr int K4 = 32;         // 4*k candidates
constexpr int KSTH = 260;      // K LDS row stride in halves (520 B -> <=2-way banks)
constexpr int VTS = 72;        // V LDS 4x16-subtile stride in halves (144 B: 16B-aligned, bank-spread)
constexpr int KST = 258;       // fp32 fallback stride

typedef _Float16 half2_t __attribute__((ext_vector_type(2)));
typedef unsigned u32x2 __attribute__((ext_vector_type(2)));

#if defined(__has_builtin)
#if __has_builtin(__builtin_amdgcn_fdot2)
#define HAVE_FDOT2 1
#endif
#endif

__device__ __forceinline__ float fdot2_acc(half2_t a, half2_t b, float c) {
#ifdef HAVE_FDOT2
  return __builtin_amdgcn_fdot2(a, b, c, false);
#else
  return c + (float)a.x * (float)b.x + (float)a.y * (float)b.y;
#endif
}

// gfx950 HW transpose read: per lane, 4 f16 elements at +0,+16,+32,+48 halves
// from the lane's own address (no internal lane offset; m162).  Flat addresses
// into LDS carry the byte offset in the low 32 bits, so truncation yields the
// DS address.
__device__ __forceinline__ u32x2 ds_read_tr_b16(const __half* p) {
  u32x2 r;
  unsigned a = (unsigned)(unsigned long long)p;
  asm volatile("ds_read_b64_tr_b16 %0, %1" : "=v"(r) : "v"(a));
  return r;
}

// ---------------------------------------------------------------------------
// Pass 1: transpose q/k/v [b, C, PIX] -> fp16 [b, PIX, C] in workspace.
// grid = (PIX/64, C/64, 6)  z: 0,1=q(b) 2,3=k(b) 4,5=v(b)
// ---------------------------------------------------------------------------
__global__ __launch_bounds__(256) void transpose_qkv_kernel(
    const float* __restrict__ q, const float* __restrict__ k,
    const float* __restrict__ v, __half* __restrict__ qT,
    __half* __restrict__ kT, __half* __restrict__ vT)
{
  __shared__ float tile[64 * 65];
  const int z = blockIdx.z;
  const int b = z & 1;
  const int arr = z >> 1;   // 0=q, 1=k, 2=v
  const float* src = (arr == 0 ? q : arr == 1 ? k : v) + (size_t)b * C * PIX;
  __half* dst = (arr == 0 ? qT : arr == 1 ? kT : vT) + (size_t)b * PIX * C;

  const int p0 = blockIdx.x * 64;
  const int c0 = blockIdx.y * 64;
  const int t15 = threadIdx.x & 15;
  const int thi4 = threadIdx.x >> 4;   // 0..15

#pragma unroll
  for (int r = 0; r < 4; ++r) {
    const int ch = thi4 + r * 16;      // channel row
    const int p4 = t15 * 4;            // pixel start
    float4 f = *(const float4*)&src[(size_t)(c0 + ch) * PIX + p0 + p4];
    tile[(p4 + 0) * 65 + ch] = f.x;
    tile[(p4 + 1) * 65 + ch] = f.y;
    tile[(p4 + 2) * 65 + ch] = f.z;
    tile[(p4 + 3) * 65 + ch] = f.w;
  }
  __syncthreads();

  const int t7 = threadIdx.x & 7;
  const int th8 = threadIdx.x >> 3;  // 0..31
#pragma unroll
  for (int r = 0; r < 2; ++r) {
    const int p = th8 + r * 32;
    const int c8 = t7 * 8;
    const float* tr = &tile[p * 65 + c8];
    __half2 h0 = __floats2half2_rn(tr[0], tr[1]);
    __half2 h1 = __floats2half2_rn(tr[2], tr[3]);
    __half2 h2 = __floats2half2_rn(tr[4], tr[5]);
    __half2 h3 = __floats2half2_rn(tr[6], tr[7]);
    uint4 u;
    u.x = *(unsigned*)&h0; u.y = *(unsigned*)&h1;
    u.z = *(unsigned*)&h2; u.w = *(unsigned*)&h3;
    *(uint4*)&dst[(size_t)(p0 + p) * C + c0 + c8] = u;   // 16B aligned
  }
}

// ---------------------------------------------------------------------------
// Pass 2: attention. One block per (b, l). All of q/K/V fp16 from ws.
// R4 cooperative-staging structure; this round: PV via ds_read_b64_tr_b16
// (HW transpose read) from a 4x16-subtiled V layout + probs relayout
// [h][t][m] so PV runs on v_dot2_f32_f16.  DS ops/lane 106 -> 65.
// LDS: kvh union(K rows 16,640 B | V subtiles 18,432 B) + qph 2,048 B
//    = 20,480 B -> 8 blocks/CU exactly (160 KiB).
// ---------------------------------------------------------------------------
__global__ __launch_bounds__(256, 8) void cascade_attn_f16(
    const __half* __restrict__ qT,     // [2, PIX, C] fp16
    const __half* __restrict__ kT,
    const __half* __restrict__ vT,
    const int* __restrict__ topk,      // [2,4096,8,2] int32
    const float* __restrict__ relp,    // [2,8,128,128,32] fp32
    float* __restrict__ out_msg,       // [2,16384,256]
    float* __restrict__ out_idx)       // [2,16384,32] (float values)
{
  // union: K rows [K4][KSTH] = 8320 halves; V subtiles 128*VTS = 9216 halves
  __shared__ __half kvh[128 * VTS];    // 18,432 B
  __shared__ __half qph[4 * C];        // q fp16 [t][c]; after QK: probs [h][t][m]

  const int tid = threadIdx.x;
  const int bid = blockIdx.x;
  const int b = bid >> 12;
  const int l = bid & (LBLK - 1);
  const int by = l >> 6, bx = l & 63;
  const int r0 = by * 2, c0 = bx * 2;

  const int* tp = topk + ((size_t)b * LBLK + l) * 16;

  const int h = tid >> 5;   // head
  const int m = tid & 31;   // candidate (QK) / head-dim lane j (PV)

  // ---- stage q: 4 pixels x 256 contiguous halves; 1 uint2 (4 halves)/thread ----
  {
    const int t = tid >> 6, ln = tid & 63;
    const int pix = r0 * W0 + c0 + (t >> 1) * W0 + (t & 1);
    uint2 f = *(const uint2*)&qT[((size_t)b * PIX + pix) * C + ln * 4];
    *(uint2*)&qph[t * C + ln * 4] = f;
  }

  // ---- candidate pixel for this thread's cooperative gather slice ----
  const int p = tid >> 3;        // candidate 0..31
  const int ln8 = tid & 7;
  const int jj = p >> 2, po = p & 3;
  const int gpix = (tp[jj * 2] * 2 + (po >> 1)) * W0 + tp[jj * 2 + 1] * 2 + (po & 1);

  // ---- stage gathered K: 4 x uint4 (8 halves each) per thread ----
  {
    const __half* src = &kT[((size_t)b * PIX + gpix) * C + ln8 * 8];
#pragma unroll
    for (int i = 0; i < 4; ++i) {
      uint4 f = *(const uint4*)(src + i * 64);      // 16B aligned
      __half* dst = &kvh[p * KSTH + ln8 * 8 + i * 64];
      *(uint2*)dst = make_uint2(f.x, f.y);          // 8B aligned (row = 520 B)
      *(uint2*)(dst + 4) = make_uint2(f.z, f.w);
    }
  }

  // ---- prefetch gathered V into registers (latency hides behind QK) ----
  uint4 vreg[4];
  {
    const __half* src = &vT[((size_t)b * PIX + gpix) * C + ln8 * 8];
#pragma unroll
    for (int i = 0; i < 4; ++i) vreg[i] = *(const uint4*)(src + i * 64);
  }

  // ---- prefetch rel_pos for this (h,m): 4 floats, coalesced over m ----
  const size_t rb = ((((size_t)b * NH + h) * H0 + r0) * W0 + c0) * K4 + m;
  float rl0 = relp[rb];
  float rl1 = relp[rb + K4];
  float rl2 = relp[rb + (size_t)W0 * K4];
  float rl3 = relp[rb + (size_t)W0 * K4 + K4];

  // ---- up_idx output: 4 pixels x 32 m per block ----
  if (tid < 128) {
    const int mm = tid & 31, t = tid >> 5;
    const int j2 = mm >> 2, o2 = mm & 3;
    const int pix = (tp[j2 * 2] * 2 + (o2 >> 1)) * W0 + tp[j2 * 2 + 1] * 2 + (o2 & 1);
    const int prow = r0 + (t >> 1), pcol = c0 + (t & 1);
    out_idx[((size_t)b * PIX + prow * W0 + pcol) * K4 + mm] = (float)pix;
  }
  __syncthreads();   // (1) q + K staged

  // ---- load K fragment from LDS: K[m][h*32..+31] as 16 half2 ----
  uint2 kw[8];
  {
    const __half* kbase = &kvh[m * KSTH + h * D];   // 8B aligned
#pragma unroll
    for (int i = 0; i < 8; ++i) kw[i] = *(const uint2*)(kbase + i * 4);
  }
  const half2_t* kh = (const half2_t*)kw;           // 16 half2

  // ---- QK via fdot2: s[t] = q[t,h,:] . K[m,h,:] ----
  float acc[4] = {0.f, 0.f, 0.f, 0.f};
#pragma unroll
  for (int t = 0; t < 4; ++t) {
    uint4 qw[2];
    const uint4* qf = (const uint4*)&qph[t * C + h * D];  // 16B aligned, broadcast
    qw[0] = qf[0];
    qw[1] = qf[1];
    const half2_t* qh2 = (const half2_t*)qw;        // 8 half2
    uint4 qw2[2];
    qw2[0] = qf[2];
    qw2[1] = qf[3];
    const half2_t* qh2b = (const half2_t*)qw2;      // 8 half2
#pragma unroll
    for (int i = 0; i < 8; ++i) acc[t] = fdot2_acc(qh2[i], kh[i], acc[t]);
#pragma unroll
    for (int i = 0; i < 8; ++i) acc[t] = fdot2_acc(qh2b[i], kh[8 + i], acc[t]);
  }

  const float scale = 0.17677669529663687f;  // 1/sqrt(32)
  float sv[4];
  sv[0] = acc[0] * scale + rl0;
  sv[1] = acc[1] * scale + rl1;
  sv[2] = acc[2] * scale + rl2;
  sv[3] = acc[3] * scale + rl3;

  // ---- softmax over m (32-lane xor shuffles stay inside the m group) ----
  float pr4[4];
#pragma unroll
  for (int t = 0; t < 4; ++t) {
    float x = sv[t];
    float mx = x;
#pragma unroll
    for (int off = 16; off > 0; off >>= 1) mx = fmaxf(mx, __shfl_xor(mx, off));
    float pbit = __expf(x - mx);
    float sm = pbit;
#pragma unroll
    for (int off = 16; off > 0; off >>= 1) sm += __shfl_xor(sm, off);
    pr4[t] = pbit / sm;
  }
  __syncthreads();   // (2) all QK reads of qph & kvh complete

  // ---- write probs fp16 into qph (q dead), layout [h][t][m] (32 contiguous) ----
#pragma unroll
  for (int t = 0; t < 4; ++t)
    qph[h * 128 + t * 32 + m] = __float2half(pr4[t]);

  // ---- write V into kvh (K dead) as 4x16 subtiles: tile T=(p/4)*16+(c/16),
  //      element [T*VTS + (p&3)*16 + (c&15)]; 4 x b128 per thread ----
#pragma unroll
  for (int i = 0; i < 4; ++i) {
    const int T = (p >> 2) * 16 + (ln8 >> 1) + i * 4;
    __half* dst = &kvh[T * VTS + (p & 3) * 16 + (ln8 & 1) * 8];
    *(uint4*)dst = vreg[i];   // 16B aligned: 144*T + 32*(p&3) + 16*(ln8&1)
  }
  __syncthreads();   // (3) probs + V visible

  // ---- PV: out[t,h,j] = sum_m A[t,h,m] * V[m,h,j]; V column via tr-reads ----
  const int cb = (h * D + m) >> 4;    // channel block of this lane's column
  const int cin = m & 15;             // position within 16-wide subtile
  u32x2 vtr[8];
#pragma unroll
  for (int g = 0; g < 8; ++g)
    vtr[g] = ds_read_tr_b16(&kvh[(g * 16 + cb) * VTS + cin]);  // rows 4g..4g+3
  asm volatile("s_waitcnt lgkmcnt(0)" ::: "memory");
  __builtin_amdgcn_sched_barrier(0);   // rule #18: keep consumers below the wait

  float oacc[4];
#pragma unroll
  for (int t = 0; t < 4; ++t) {
    unsigned pw[8];
    {
      const uint4* pp = (const uint4*)&qph[h * 128 + t * 32];  // broadcast per h
      uint4 A = pp[0], B = pp[1];
      pw[0] = A.x; pw[1] = A.y; pw[2] = A.z; pw[3] = A.w;
      pw[4] = B.x; pw[5] = B.y; pw[6] = B.z; pw[7] = B.w;
    }
    float s = 0.f;
#pragma unroll
    for (int g = 0; g < 8; ++g) {
      unsigned vlo = vtr[g][0], vhi = vtr[g][1];   // (m=4g,4g+1), (m=4g+2,4g+3)
      s = fdot2_acc(__builtin_bit_cast(half2_t, pw[2 * g]),
                    __builtin_bit_cast(half2_t, vlo), s);
      s = fdot2_acc(__builtin_bit_cast(half2_t, pw[2 * g + 1]),
                    __builtin_bit_cast(half2_t, vhi), s);
    }
    oacc[t] = s;
  }

  const size_t ob = ((size_t)b * PIX + (size_t)r0 * W0 + c0) * C + h * D + m;
  out_msg[ob] = oacc[0];
  out_msg[ob + C] = oacc[1];
  out_msg[ob + (size_t)W0 * C] = oacc[2];
  out_msg[ob + (size_t)W0 * C + C] = oacc[3];
}

// ---------------------------------------------------------------------------
// Fallback (Round-1 kernel, known correct): used only if ws too small.
// ---------------------------------------------------------------------------
__global__ __launch_bounds__(256) void cascade_attn_fallback(
    const float* __restrict__ query, const float* __restrict__ key,
    const float* __restrict__ value, const int* __restrict__ topk,
    const float* __restrict__ relp, float* __restrict__ out_msg,
    float* __restrict__ out_idx)
{
  __shared__ float kv[K4 * KST];
  __shared__ float qs[4 * C];
  __shared__ float as_[NH * K4 * 4];

  const int tid = threadIdx.x;
  const int bid = blockIdx.x;
  const int b = bid >> 12;
  const int l = bid & (LBLK - 1);
  const int by = l >> 6, bx = l & 63;
  const int r0 = by * 2, c0 = bx * 2;

  const size_t plane = (size_t)PIX;
  const float* qb = query + (size_t)b * C * plane;
  const float* kb = key + (size_t)b * C * plane;
  const float* vb = value + (size_t)b * C * plane;
  const int* tp = topk + ((size_t)b * LBLK + l) * 16;

  {
    const float* qp = qb + (size_t)tid * plane + r0 * W0 + c0;
    float2 a = *(const float2*)qp;
    float2 bb = *(const float2*)(qp + W0);
    qs[0 * C + tid] = a.x; qs[1 * C + tid] = a.y;
    qs[2 * C + tid] = bb.x; qs[3 * C + tid] = bb.y;
  }
#pragma unroll
  for (int it = 0; it < 16; ++it) {
    const int jj = it >> 1, x = it & 1;
    const int pr = tp[jj * 2] * 2 + x;
    const int pc = tp[jj * 2 + 1] * 2;
    float2 f = *(const float2*)(kb + (size_t)tid * plane + pr * W0 + pc);
    const int m0 = jj * 4 + x * 2;
    kv[m0 * KST + tid] = f.x;
    kv[(m0 + 1) * KST + tid] = f.y;
  }
  if (tid < 128) {
    const int m = tid & 31, t = tid >> 5;
    const int jj = m >> 2, o = m & 3;
    const int pix = (tp[jj * 2] * 2 + (o >> 1)) * W0 + tp[jj * 2 + 1] * 2 + (o & 1);
    const int prow = r0 + (t >> 1), pcol = c0 + (t & 1);
    out_idx[((size_t)b * plane + prow * W0 + pcol) * K4 + m] = (float)pix;
  }
  __syncthreads();

  const int h = tid >> 5;
  const int m = tid & 31;
  float a0 = 0.f, a1 = 0.f, a2 = 0.f, a3 = 0.f;
#pragma unroll
  for (int dq = 0; dq < 8; ++dq) {
    const int off = h * D + dq * 4;
    float4 q0 = *(const float4*)&qs[0 * C + off];
    float4 q1 = *(const float4*)&qs[1 * C + off];
    float4 q2 = *(const float4*)&qs[2 * C + off];
    float4 q3 = *(const float4*)&qs[3 * C + off];
    float2 ka = *(const float2*)&kv[m * KST + off];
    float2 kc = *(const float2*)&kv[m * KST + off + 2];
    a0 += q0.x * ka.x + q0.y * ka.y + q0.z * kc.x + q0.w * kc.y;
    a1 += q1.x * ka.x + q1.y * ka.y + q1.z * kc.x + q1.w * kc.y;
    a2 += q2.x * ka.x + q2.y * ka.y + q2.z * kc.x + q2.w * kc.y;
    a3 += q3.x * ka.x + q3.y * ka.y + q3.z * kc.x + q3.w * kc.y;
  }
  const float scale = 0.17677669529663687f;
  const size_t rb = ((((size_t)b * NH + h) * H0 + r0) * W0 + c0) * K4 + m;
  float sv[4];
  sv[0] = a0 * scale + relp[rb];
  sv[1] = a1 * scale + relp[rb + K4];
  sv[2] = a2 * scale + relp[rb + (size_t)W0 * K4];
  sv[3] = a3 * scale + relp[rb + (size_t)W0 * K4 + K4];
  float pr4[4];
#pragma unroll
  for (int t = 0; t < 4; ++t) {
    float x = sv[t];
    float mx = x;
#pragma unroll
    for (int off = 16; off > 0; off >>= 1) mx = fmaxf(mx, __shfl_xor(mx, off));
    float pbit = __expf(x - mx);
    float sm = pbit;
#pragma unroll
    for (int off = 16; off > 0; off >>= 1) sm += __shfl_xor(sm, off);
    pr4[t] = pbit / sm;
  }
  *(float4*)&as_[tid * 4] = make_float4(pr4[0], pr4[1], pr4[2], pr4[3]);
  __syncthreads();
#pragma unroll
  for (int it = 0; it < 16; ++it) {
    const int jj = it >> 1, x = it & 1;
    const int pr = tp[jj * 2] * 2 + x;
    const int pc = tp[jj * 2 + 1] * 2;
    float2 f = *(const float2*)(vb + (size_t)tid * plane + pr * W0 + pc);
    const int m0 = jj * 4 + x * 2;
    kv[m0 * KST + tid] = f.x;
    kv[(m0 + 1) * KST + tid] = f.y;
  }
  __syncthreads();
  float o0 = 0.f, o1 = 0.f, o2 = 0.f, o3 = 0.f;
#pragma unroll
  for (int mm = 0; mm < 32; ++mm) {
    float4 a4 = *(const float4*)&as_[(h * K4 + mm) * 4];
    float vv = kv[mm * KST + h * D + m];
    o0 += a4.x * vv; o1 += a4.y * vv; o2 += a4.z * vv; o3 += a4.w * vv;
  }
  const size_t ob = ((size_t)b * plane + (size_t)r0 * W0 + c0) * C + h * D + m;
  out_msg[ob] = o0;
  out_msg[ob + C] = o1;
  out_msg[ob + (size_t)W0 * C] = o2;
  out_msg[ob + (size_t)W0 * C + C] = o3;
}

extern "C" void kernel_launch(void* const* d_in, const int* in_sizes, int n_in,
                              void* d_out, int out_size, void* d_ws, size_t ws_size,
                              hipStream_t stream) {
  const float* q = (const float*)d_in[0];
  const float* k = (const float*)d_in[1];
  const float* v = (const float*)d_in[2];
  const int* tp = (const int*)d_in[3];
  const float* rp = (const float*)d_in[4];

  float* out_msg = (float*)d_out;
  float* out_idx = out_msg + (size_t)2 * PIX * C;

  const size_t n_elem = (size_t)2 * PIX * C;
  const size_t needed = 3 * n_elem * sizeof(__half);  // 50.3 MB
  if (ws_size >= needed) {
    __half* qT = (__half*)d_ws;
    __half* kT = qT + n_elem;
    __half* vT = kT + n_elem;
    dim3 tg(PIX / 64, C / 64, 6);
    hipLaunchKernelGGL(transpose_qkv_kernel, tg, dim3(256), 0, stream,
                       q, k, v, qT, kT, vT);
    hipLaunchKernelGGL(cascade_attn_f16, dim3(2 * LBLK), dim3(256), 0, stream,
                       qT, kT, vT, tp, rp, out_msg, out_idx);
  } else {
    hipLaunchKernelGGL(cascade_attn_fallback, dim3(2 * LBLK), dim3(256), 0, stream,
                       q, k, v, tp, rp, out_msg, out_idx);
  }
}

// Round 3
// 248.108 us; speedup vs baseline: 1.0018x; 1.0018x over previous
//
#include <hip/hip_runtime.h>
#include <hip/hip_fp16.h>
#include <math.h>

// Problem constants (fixed by the reference setup_inputs)
constexpr int NH = 8;     // heads
constexpr int D = 32;     // head dim (c/nh)
constexpr int C = 256;    // channels
constexpr int H0 = 128;
constexpr int W0 = 128;
constexpr int PIX = H0 * W0;   // 16384
constexpr int LBLK = 4096;     // (H0/2)*(W0/2)
constexpr int K4 = 32;         // 4*k candidates
constexpr int KSTH = 260;      // K LDS row stride in halves (520 B -> <=2-way banks)
constexpr int VTS = 72;        // V LDS 4x16-subtile stride in halves (144 B: 16B-aligned, bank-spread)
constexpr int KST = 258;       // fp32 fallback stride

typedef _Float16 half2_t __attribute__((ext_vector_type(2)));
typedef unsigned u32x2 __attribute__((ext_vector_type(2)));

#if defined(__has_builtin)
#if __has_builtin(__builtin_amdgcn_fdot2)
#define HAVE_FDOT2 1
#endif
#endif

__device__ __forceinline__ float fdot2_acc(half2_t a, half2_t b, float c) {
#ifdef HAVE_FDOT2
  return __builtin_amdgcn_fdot2(a, b, c, false);
#else
  return c + (float)a.x * (float)b.x + (float)a.y * (float)b.y;
#endif
}

// gfx950 HW transpose read: per lane, 4 f16 elements at +0,+16,+32,+48 halves
// from the lane's own address.  LDS flat-aperture offset lives in the low 32
// bits, so truncation yields the DS address.
__device__ __forceinline__ u32x2 ds_read_tr_b16(const __half* p) {
  u32x2 r;
  unsigned a = (unsigned)(unsigned long long)p;
  asm volatile("ds_read_b64_tr_b16 %0, %1" : "=v"(r) : "v"(a));
  return r;
}

// ---------------------------------------------------------------------------
// Pass 1: transpose q/k/v [b, C, PIX] -> fp16 [b, PIX, C] in workspace.
// grid = (PIX/64, C/64, 6)  z: 0,1=q(b) 2,3=k(b) 4,5=v(b)
// ---------------------------------------------------------------------------
__global__ __launch_bounds__(256) void transpose_qkv_kernel(
    const float* __restrict__ q, const float* __restrict__ k,
    const float* __restrict__ v, __half* __restrict__ qT,
    __half* __restrict__ kT, __half* __restrict__ vT)
{
  __shared__ float tile[64 * 65];
  const int z = blockIdx.z;
  const int b = z & 1;
  const int arr = z >> 1;   // 0=q, 1=k, 2=v
  const float* src = (arr == 0 ? q : arr == 1 ? k : v) + (size_t)b * C * PIX;
  __half* dst = (arr == 0 ? qT : arr == 1 ? kT : vT) + (size_t)b * PIX * C;

  const int p0 = blockIdx.x * 64;
  const int c0 = blockIdx.y * 64;
  const int t15 = threadIdx.x & 15;
  const int thi4 = threadIdx.x >> 4;   // 0..15

#pragma unroll
  for (int r = 0; r < 4; ++r) {
    const int ch = thi4 + r * 16;      // channel row
    const int p4 = t15 * 4;            // pixel start
    float4 f = *(const float4*)&src[(size_t)(c0 + ch) * PIX + p0 + p4];
    tile[(p4 + 0) * 65 + ch] = f.x;
    tile[(p4 + 1) * 65 + ch] = f.y;
    tile[(p4 + 2) * 65 + ch] = f.z;
    tile[(p4 + 3) * 65 + ch] = f.w;
  }
  __syncthreads();

  const int t7 = threadIdx.x & 7;
  const int th8 = threadIdx.x >> 3;  // 0..31
#pragma unroll
  for (int r = 0; r < 2; ++r) {
    const int p = th8 + r * 32;
    const int c8 = t7 * 8;
    const float* tr = &tile[p * 65 + c8];
    __half2 h0 = __floats2half2_rn(tr[0], tr[1]);
    __half2 h1 = __floats2half2_rn(tr[2], tr[3]);
    __half2 h2 = __floats2half2_rn(tr[4], tr[5]);
    __half2 h3 = __floats2half2_rn(tr[6], tr[7]);
    uint4 u;
    u.x = *(unsigned*)&h0; u.y = *(unsigned*)&h1;
    u.z = *(unsigned*)&h2; u.w = *(unsigned*)&h3;
    *(uint4*)&dst[(size_t)(p0 + p) * C + c0 + c8] = u;   // 16B aligned
  }
}

// ---------------------------------------------------------------------------
// Pass 2: attention. One block per (b, l). All of q/K/V fp16 from ws.
// PV via ds_read_b64_tr_b16 (HW transpose read) from a 4x16-subtiled V
// layout + probs relayout [h][t][m] so PV runs on v_dot2_f32_f16.
// DS ops/lane 106 -> 65.  LDS: 18,432 + 2,048 = 20,480 B -> 8 blocks/CU.
// R2 fix: probs row is 32 halves = 4 x uint4 -> pw[16] (pw[8] OOB was UB:
// scratch spills +128 MB writes, wrong values).
// ---------------------------------------------------------------------------
__global__ __launch_bounds__(256, 8) void cascade_attn_f16(
    const __half* __restrict__ qT,     // [2, PIX, C] fp16
    const __half* __restrict__ kT,
    const __half* __restrict__ vT,
    const int* __restrict__ topk,      // [2,4096,8,2] int32
    const float* __restrict__ relp,    // [2,8,128,128,32] fp32
    float* __restrict__ out_msg,       // [2,16384,256]
    float* __restrict__ out_idx)       // [2,16384,32] (float values)
{
  // union: K rows [K4][KSTH] = 8320 halves; V subtiles 128*VTS = 9216 halves
  __shared__ __half kvh[128 * VTS];    // 18,432 B
  __shared__ __half qph[4 * C];        // q fp16 [t][c]; after QK: probs [h][t][m]

  const int tid = threadIdx.x;
  const int bid = blockIdx.x;
  const int b = bid >> 12;
  const int l = bid & (LBLK - 1);
  const int by = l >> 6, bx = l & 63;
  const int r0 = by * 2, c0 = bx * 2;

  const int* tp = topk + ((size_t)b * LBLK + l) * 16;

  const int h = tid >> 5;   // head
  const int m = tid & 31;   // candidate (QK) / head-dim lane j (PV)

  // ---- stage q: 4 pixels x 256 contiguous halves; 1 uint2 (4 halves)/thread ----
  {
    const int t = tid >> 6, ln = tid & 63;
    const int pix = r0 * W0 + c0 + (t >> 1) * W0 + (t & 1);
    uint2 f = *(const uint2*)&qT[((size_t)b * PIX + pix) * C + ln * 4];
    *(uint2*)&qph[t * C + ln * 4] = f;
  }

  // ---- candidate pixel for this thread's cooperative gather slice ----
  const int p = tid >> 3;        // candidate 0..31
  const int ln8 = tid & 7;
  const int jj = p >> 2, po = p & 3;
  const int gpix = (tp[jj * 2] * 2 + (po >> 1)) * W0 + tp[jj * 2 + 1] * 2 + (po & 1);

  // ---- stage gathered K: 4 x uint4 (8 halves each) per thread ----
  {
    const __half* src = &kT[((size_t)b * PIX + gpix) * C + ln8 * 8];
#pragma unroll
    for (int i = 0; i < 4; ++i) {
      uint4 f = *(const uint4*)(src + i * 64);      // 16B aligned
      __half* dst = &kvh[p * KSTH + ln8 * 8 + i * 64];
      *(uint2*)dst = make_uint2(f.x, f.y);          // 8B aligned (row = 520 B)
      *(uint2*)(dst + 4) = make_uint2(f.z, f.w);
    }
  }

  // ---- prefetch gathered V into registers (latency hides behind QK) ----
  uint4 vreg[4];
  {
    const __half* src = &vT[((size_t)b * PIX + gpix) * C + ln8 * 8];
#pragma unroll
    for (int i = 0; i < 4; ++i) vreg[i] = *(const uint4*)(src + i * 64);
  }

  // ---- prefetch rel_pos for this (h,m): 4 floats, coalesced over m ----
  const size_t rb = ((((size_t)b * NH + h) * H0 + r0) * W0 + c0) * K4 + m;
  float rl0 = relp[rb];
  float rl1 = relp[rb + K4];
  float rl2 = relp[rb + (size_t)W0 * K4];
  float rl3 = relp[rb + (size_t)W0 * K4 + K4];

  // ---- up_idx output: 4 pixels x 32 m per block ----
  if (tid < 128) {
    const int mm = tid & 31, t = tid >> 5;
    const int j2 = mm >> 2, o2 = mm & 3;
    const int pix = (tp[j2 * 2] * 2 + (o2 >> 1)) * W0 + tp[j2 * 2 + 1] * 2 + (o2 & 1);
    const int prow = r0 + (t >> 1), pcol = c0 + (t & 1);
    out_idx[((size_t)b * PIX + prow * W0 + pcol) * K4 + mm] = (float)pix;
  }
  __syncthreads();   // (1) q + K staged

  // ---- load K fragment from LDS: K[m][h*32..+31] as 16 half2 ----
  uint2 kw[8];
  {
    const __half* kbase = &kvh[m * KSTH + h * D];   // 8B aligned
#pragma unroll
    for (int i = 0; i < 8; ++i) kw[i] = *(const uint2*)(kbase + i * 4);
  }
  const half2_t* kh = (const half2_t*)kw;           // 16 half2

  // ---- QK via fdot2: s[t] = q[t,h,:] . K[m,h,:] ----
  float acc[4] = {0.f, 0.f, 0.f, 0.f};
#pragma unroll
  for (int t = 0; t < 4; ++t) {
    uint4 qw[2];
    const uint4* qf = (const uint4*)&qph[t * C + h * D];  // 16B aligned, broadcast
    qw[0] = qf[0];
    qw[1] = qf[1];
    const half2_t* qh2 = (const half2_t*)qw;        // 8 half2
    uint4 qw2[2];
    qw2[0] = qf[2];
    qw2[1] = qf[3];
    const half2_t* qh2b = (const half2_t*)qw2;      // 8 half2
#pragma unroll
    for (int i = 0; i < 8; ++i) acc[t] = fdot2_acc(qh2[i], kh[i], acc[t]);
#pragma unroll
    for (int i = 0; i < 8; ++i) acc[t] = fdot2_acc(qh2b[i], kh[8 + i], acc[t]);
  }

  const float scale = 0.17677669529663687f;  // 1/sqrt(32)
  float sv[4];
  sv[0] = acc[0] * scale + rl0;
  sv[1] = acc[1] * scale + rl1;
  sv[2] = acc[2] * scale + rl2;
  sv[3] = acc[3] * scale + rl3;

  // ---- softmax over m (32-lane xor shuffles stay inside the m group) ----
  float pr4[4];
#pragma unroll
  for (int t = 0; t < 4; ++t) {
    float x = sv[t];
    float mx = x;
#pragma unroll
    for (int off = 16; off > 0; off >>= 1) mx = fmaxf(mx, __shfl_xor(mx, off));
    float pbit = __expf(x - mx);
    float sm = pbit;
#pragma unroll
    for (int off = 16; off > 0; off >>= 1) sm += __shfl_xor(sm, off);
    pr4[t] = pbit / sm;
  }
  __syncthreads();   // (2) all QK reads of qph & kvh complete

  // ---- write probs fp16 into qph (q dead), layout [h][t][m] (32 contiguous) ----
#pragma unroll
  for (int t = 0; t < 4; ++t)
    qph[h * 128 + t * 32 + m] = __float2half(pr4[t]);

  // ---- write V into kvh (K dead) as 4x16 subtiles: tile T=(p/4)*16+(c/16),
  //      element [T*VTS + (p&3)*16 + (c&15)]; 4 x b128 per thread ----
#pragma unroll
  for (int i = 0; i < 4; ++i) {
    const int T = (p >> 2) * 16 + (ln8 >> 1) + i * 4;
    __half* dst = &kvh[T * VTS + (p & 3) * 16 + (ln8 & 1) * 8];
    *(uint4*)dst = vreg[i];   // 16B aligned: 144*T + 32*(p&3) + 16*(ln8&1)
  }
  __syncthreads();   // (3) probs + V visible

  // ---- PV: out[t,h,j] = sum_m A[t,h,m] * V[m,h,j]; V column via tr-reads ----
  const int cb = (h * D + m) >> 4;    // channel block of this lane's column
  const int cin = m & 15;             // position within 16-wide subtile
  u32x2 vtr[8];
#pragma unroll
  for (int g = 0; g < 8; ++g)
    vtr[g] = ds_read_tr_b16(&kvh[(g * 16 + cb) * VTS + cin]);  // rows 4g..4g+3
  asm volatile("s_waitcnt lgkmcnt(0)" ::: "memory");
  __builtin_amdgcn_sched_barrier(0);   // rule #18: keep consumers below the wait

  float oacc[4];
#pragma unroll
  for (int t = 0; t < 4; ++t) {
    // probs row = 32 halves = 16 dwords = 4 x uint4 (R2 fix: was 8 -> OOB UB)
    unsigned pw[16];
    {
      const uint4* pp = (const uint4*)&qph[h * 128 + t * 32];  // broadcast per h
      uint4 A = pp[0], B = pp[1], Cq = pp[2], Dq = pp[3];
      pw[0] = A.x;  pw[1] = A.y;  pw[2] = A.z;  pw[3] = A.w;
      pw[4] = B.x;  pw[5] = B.y;  pw[6] = B.z;  pw[7] = B.w;
      pw[8] = Cq.x; pw[9] = Cq.y; pw[10] = Cq.z; pw[11] = Cq.w;
      pw[12] = Dq.x; pw[13] = Dq.y; pw[14] = Dq.z; pw[15] = Dq.w;
    }
    float s = 0.f;
#pragma unroll
    for (int g = 0; g < 8; ++g) {
      unsigned vlo = vtr[g][0], vhi = vtr[g][1];   // (m=4g,4g+1), (m=4g+2,4g+3)
      s = fdot2_acc(__builtin_bit_cast(half2_t, pw[2 * g]),
                    __builtin_bit_cast(half2_t, vlo), s);
      s = fdot2_acc(__builtin_bit_cast(half2_t, pw[2 * g + 1]),
                    __builtin_bit_cast(half2_t, vhi), s);
    }
    oacc[t] = s;
  }

  const size_t ob = ((size_t)b * PIX + (size_t)r0 * W0 + c0) * C + h * D + m;
  out_msg[ob] = oacc[0];
  out_msg[ob + C] = oacc[1];
  out_msg[ob + (size_t)W0 * C] = oacc[2];
  out_msg[ob + (size_t)W0 * C + C] = oacc[3];
}

// ---------------------------------------------------------------------------
// Fallback (Round-1 kernel, known correct): used only if ws too small.
// ---------------------------------------------------------------------------
__global__ __launch_bounds__(256) void cascade_attn_fallback(
    const float* __restrict__ query, const float* __restrict__ key,
    const float* __restrict__ value, const int* __restrict__ topk,
    const float* __restrict__ relp, float* __restrict__ out_msg,
    float* __restrict__ out_idx)
{
  __shared__ float kv[K4 * KST];
  __shared__ float qs[4 * C];
  __shared__ float as_[NH * K4 * 4];

  const int tid = threadIdx.x;
  const int bid = blockIdx.x;
  const int b = bid >> 12;
  const int l = bid & (LBLK - 1);
  const int by = l >> 6, bx = l & 63;
  const int r0 = by * 2, c0 = bx * 2;

  const size_t plane = (size_t)PIX;
  const float* qb = query + (size_t)b * C * plane;
  const float* kb = key + (size_t)b * C * plane;
  const float* vb = value + (size_t)b * C * plane;
  const int* tp = topk + ((size_t)b * LBLK + l) * 16;

  {
    const float* qp = qb + (size_t)tid * plane + r0 * W0 + c0;
    float2 a = *(const float2*)qp;
    float2 bb = *(const float2*)(qp + W0);
    qs[0 * C + tid] = a.x; qs[1 * C + tid] = a.y;
    qs[2 * C + tid] = bb.x; qs[3 * C + tid] = bb.y;
  }
#pragma unroll
  for (int it = 0; it < 16; ++it) {
    const int jj = it >> 1, x = it & 1;
    const int pr = tp[jj * 2] * 2 + x;
    const int pc = tp[jj * 2 + 1] * 2;
    float2 f = *(const float2*)(kb + (size_t)tid * plane + pr * W0 + pc);
    const int m0 = jj * 4 + x * 2;
    kv[m0 * KST + tid] = f.x;
    kv[(m0 + 1) * KST + tid] = f.y;
  }
  if (tid < 128) {
    const int m = tid & 31, t = tid >> 5;
    const int jj = m >> 2, o = m & 3;
    const int pix = (tp[jj * 2] * 2 + (o >> 1)) * W0 + tp[jj * 2 + 1] * 2 + (o & 1);
    const int prow = r0 + (t >> 1), pcol = c0 + (t & 1);
    out_idx[((size_t)b * plane + prow * W0 + pcol) * K4 + m] = (float)pix;
  }
  __syncthreads();

  const int h = tid >> 5;
  const int m = tid & 31;
  float a0 = 0.f, a1 = 0.f, a2 = 0.f, a3 = 0.f;
#pragma unroll
  for (int dq = 0; dq < 8; ++dq) {
    const int off = h * D + dq * 4;
    float4 q0 = *(const float4*)&qs[0 * C + off];
    float4 q1 = *(const float4*)&qs[1 * C + off];
    float4 q2 = *(const float4*)&qs[2 * C + off];
    float4 q3 = *(const float4*)&qs[3 * C + off];
    float2 ka = *(const float2*)&kv[m * KST + off];
    float2 kc = *(const float2*)&kv[m * KST + off + 2];
    a0 += q0.x * ka.x + q0.y * ka.y + q0.z * kc.x + q0.w * kc.y;
    a1 += q1.x * ka.x + q1.y * ka.y + q1.z * kc.x + q1.w * kc.y;
    a2 += q2.x * ka.x + q2.y * ka.y + q2.z * kc.x + q2.w * kc.y;
    a3 += q3.x * ka.x + q3.y * ka.y + q3.z * kc.x + q3.w * kc.y;
  }
  const float scale = 0.17677669529663687f;
  const size_t rb = ((((size_t)b * NH + h) * H0 + r0) * W0 + c0) * K4 + m;
  float sv[4];
  sv[0] = a0 * scale + relp[rb];
  sv[1] = a1 * scale + relp[rb + K4];
  sv[2] = a2 * scale + relp[rb + (size_t)W0 * K4];
  sv[3] = a3 * scale + relp[rb + (size_t)W0 * K4 + K4];
  float pr4[4];
#pragma unroll
  for (int t = 0; t < 4; ++t) {
    float x = sv[t];
    float mx = x;
#pragma unroll
    for (int off = 16; off > 0; off >>= 1) mx = fmaxf(mx, __shfl_xor(mx, off));
    float pbit = __expf(x - mx);
    float sm = pbit;
#pragma unroll
    for (int off = 16; off > 0; off >>= 1) sm += __shfl_xor(sm, off);
    pr4[t] = pbit / sm;
  }
  *(float4*)&as_[tid * 4] = make_float4(pr4[0], pr4[1], pr4[2], pr4[3]);
  __syncthreads();
#pragma unroll
  for (int it = 0; it < 16; ++it) {
    const int jj = it >> 1, x = it & 1;
    const int pr = tp[jj * 2] * 2 + x;
    const int pc = tp[jj * 2 + 1] * 2;
    float2 f = *(const float2*)(vb + (size_t)tid * plane + pr * W0 + pc);
    const int m0 = jj * 4 + x * 2;
    kv[m0 * KST + tid] = f.x;
    kv[(m0 + 1) * KST + tid] = f.y;
  }
  __syncthreads();
  float o0 = 0.f, o1 = 0.f, o2 = 0.f, o3 = 0.f;
#pragma unroll
  for (int mm = 0; mm < 32; ++mm) {
    float4 a4 = *(const float4*)&as_[(h * K4 + mm) * 4];
    float vv = kv[mm * KST + h * D + m];
    o0 += a4.x * vv; o1 += a4.y * vv; o2 += a4.z * vv; o3 += a4.w * vv;
  }
  const size_t ob = ((size_t)b * plane + (size_t)r0 * W0 + c0) * C + h * D + m;
  out_msg[ob] = o0;
  out_msg[ob + C] = o1;
  out_msg[ob + (size_t)W0 * C] = o2;
  out_msg[ob + (size_t)W0 * C + C] = o3;
}

extern "C" void kernel_launch(void* const* d_in, const int* in_sizes, int n_in,
                              void* d_out, int out_size, void* d_ws, size_t ws_size,
                              hipStream_t stream) {
  const float* q = (const float*)d_in[0];
  const float* k = (const float*)d_in[1];
  const float* v = (const float*)d_in[2];
  const int* tp = (const int*)d_in[3];
  const float* rp = (const float*)d_in[4];

  float* out_msg = (float*)d_out;
  float* out_idx = out_msg + (size_t)2 * PIX * C;

  const size_t n_elem = (size_t)2 * PIX * C;
  const size_t needed = 3 * n_elem * sizeof(__half);  // 50.3 MB
  if (ws_size >= needed) {
    __half* qT = (__half*)d_ws;
    __half* kT = qT + n_elem;
    __half* vT = kT + n_elem;
    dim3 tg(PIX / 64, C / 64, 6);
    hipLaunchKernelGGL(transpose_qkv_kernel, tg, dim3(256), 0, stream,
                       q, k, v, qT, kT, vT);
    hipLaunchKernelGGL(cascade_attn_f16, dim3(2 * LBLK), dim3(256), 0, stream,
                       qT, kT, vT, tp, rp, out_msg, out_idx);
  } else {
    hipLaunchKernelGGL(cascade_attn_fallback, dim3(2 * LBLK), dim3(256), 0, stream,
                       q, k, v, tp, rp, out_msg, out_idx);
  }
}

// Round 5
// 232.398 us; speedup vs baseline: 1.0695x; 1.0676x over previous
//
#include <hip/hip_runtime.h>
#include <hip/hip_fp16.h>
#include <math.h>

// Problem constants (fixed by the reference setup_inputs)
constexpr int NH = 8;     // heads
constexpr int D = 32;     // head dim (c/nh)
constexpr int C = 256;    // channels
constexpr int H0 = 128;
constexpr int W0 = 128;
constexpr int PIX = H0 * W0;   // 16384
constexpr int LBLK = 4096;     // (H0/2)*(W0/2)
constexpr int K4 = 32;         // 4*k candidates
constexpr int VST = 264;       // V LDS row stride in halves (528 B: 16B-aligned, bank-shift 4)
constexpr int KST = 258;       // fp32 fallback stride

typedef _Float16 half2_t __attribute__((ext_vector_type(2)));

#if defined(__has_builtin)
#if __has_builtin(__builtin_amdgcn_fdot2)
#define HAVE_FDOT2 1
#endif
#endif

__device__ __forceinline__ float fdot2_acc(half2_t a, half2_t b, float c) {
#ifdef HAVE_FDOT2
  return __builtin_amdgcn_fdot2(a, b, c, false);
#else
  return c + (float)a.x * (float)b.x + (float)a.y * (float)b.y;
#endif
}

// ---------------------------------------------------------------------------
// Pass 1: transpose q/k/v [b, C, PIX] -> fp16 [b, PIX, C] in workspace.
// grid = (PIX/64, C/64, 6)  z: 0,1=q(b) 2,3=k(b) 4,5=v(b)
// ---------------------------------------------------------------------------
__global__ __launch_bounds__(256) void transpose_qkv_kernel(
    const float* __restrict__ q, const float* __restrict__ k,
    const float* __restrict__ v, __half* __restrict__ qT,
    __half* __restrict__ kT, __half* __restrict__ vT)
{
  __shared__ float tile[64 * 65];
  const int z = blockIdx.z;
  const int b = z & 1;
  const int arr = z >> 1;   // 0=q, 1=k, 2=v
  const float* src = (arr == 0 ? q : arr == 1 ? k : v) + (size_t)b * C * PIX;
  __half* dst = (arr == 0 ? qT : arr == 1 ? kT : vT) + (size_t)b * PIX * C;

  const int p0 = blockIdx.x * 64;
  const int c0 = blockIdx.y * 64;
  const int t15 = threadIdx.x & 15;
  const int thi4 = threadIdx.x >> 4;   // 0..15

#pragma unroll
  for (int r = 0; r < 4; ++r) {
    const int ch = thi4 + r * 16;      // channel row
    const int p4 = t15 * 4;            // pixel start
    float4 f = *(const float4*)&src[(size_t)(c0 + ch) * PIX + p0 + p4];
    tile[(p4 + 0) * 65 + ch] = f.x;
    tile[(p4 + 1) * 65 + ch] = f.y;
    tile[(p4 + 2) * 65 + ch] = f.z;
    tile[(p4 + 3) * 65 + ch] = f.w;
  }
  __syncthreads();

  const int t7 = threadIdx.x & 7;
  const int th8 = threadIdx.x >> 3;  // 0..31
#pragma unroll
  for (int r = 0; r < 2; ++r) {
    const int p = th8 + r * 32;
    const int c8 = t7 * 8;
    const float* tr = &tile[p * 65 + c8];
    __half2 h0 = __floats2half2_rn(tr[0], tr[1]);
    __half2 h1 = __floats2half2_rn(tr[2], tr[3]);
    __half2 h2 = __floats2half2_rn(tr[4], tr[5]);
    __half2 h3 = __floats2half2_rn(tr[6], tr[7]);
    uint4 u;
    u.x = *(unsigned*)&h0; u.y = *(unsigned*)&h1;
    u.z = *(unsigned*)&h2; u.w = *(unsigned*)&h3;
    *(uint4*)&dst[(size_t)(p0 + p) * C + c0 + c8] = u;   // 16B aligned
  }
}

// ---------------------------------------------------------------------------
// Pass 2: attention. One block per (b, l).  R4 redesign:
//  - q and K are loaded DIRECTLY from the fp16 workspace (each lane needs one
//    64-B line per matrix per t) -> q/K LDS staging deleted (-33 DS ops/lane).
//  - Only V (proven stride-row layout) and fp16 probs go through LDS.
//  - probs stored d-major: half[h*128 + d*8 + t*2 + (m&1)], so PV reads one
//    broadcast uint4 per candidate-pair d holding all 4 t dwords, and V pairs
//    (V[2d][c], V[2d+1][c]) feed v_dot2_f32_f16.
//  - ONE barrier (was 3).
//  DS ops/lane: 106 -> 56.  LDS: 32*264*2 + 2048 = 18,944 B -> 8 blocks/CU.
// ---------------------------------------------------------------------------
__global__ __launch_bounds__(256, 8) void cascade_attn_f16(
    const __half* __restrict__ qT,     // [2, PIX, C] fp16
    const __half* __restrict__ kT,
    const __half* __restrict__ vT,
    const int* __restrict__ topk,      // [2,4096,8,2] int32
    const float* __restrict__ relp,    // [2,8,128,128,32] fp32
    float* __restrict__ out_msg,       // [2,16384,256]
    float* __restrict__ out_idx)       // [2,16384,32] (float values)
{
  __shared__ __half vsh[K4 * VST];   // gathered V rows (16,896 B)
  __shared__ __half pph[NH * 128];   // probs fp16, d-major (2,048 B)

  const int tid = threadIdx.x;
  const int bid = blockIdx.x;
  const int b = bid >> 12;
  const int l = bid & (LBLK - 1);
  const int by = l >> 6, bx = l & 63;
  const int r0 = by * 2, c0 = bx * 2;

  const int* tp = topk + ((size_t)b * LBLK + l) * 16;

  const int h = tid >> 5;   // head
  const int m = tid & 31;   // candidate (QK) / head-dim lane j (PV)

  // ---- own-candidate pixel (for direct K load) ----
  const int gm = (tp[(m >> 2) * 2] * 2 + ((m & 3) >> 1)) * W0 +
                 tp[(m >> 2) * 2 + 1] * 2 + (m & 1);

  // ---- issue K line load: K[m][h*32..+31] = 64 B = 4 x uint4 ----
  uint4 kw4[4];
  {
    const uint4* kptr = (const uint4*)&kT[((size_t)b * PIX + gm) * C + h * D];
#pragma unroll
    for (int i = 0; i < 4; ++i) kw4[i] = kptr[i];
  }

  // ---- cooperative V gather slice -> LDS rows (proven layout) ----
  const int p = tid >> 3;        // candidate 0..31
  const int ln8 = tid & 7;
  {
    const int jj = p >> 2, po = p & 3;
    const int gp = (tp[jj * 2] * 2 + (po >> 1)) * W0 + tp[jj * 2 + 1] * 2 + (po & 1);
    const __half* src = &vT[((size_t)b * PIX + gp) * C + ln8 * 8];
#pragma unroll
    for (int i = 0; i < 4; ++i) {
      uint4 f = *(const uint4*)(src + i * 64);              // 16B aligned
      *(uint4*)&vsh[p * VST + ln8 * 8 + i * 64] = f;        // 528B row: 16B aligned
    }
  }

  // ---- prefetch rel_pos for this (h,m): 4 floats, coalesced over m ----
  const size_t rb = ((((size_t)b * NH + h) * H0 + r0) * W0 + c0) * K4 + m;
  float rl0 = relp[rb];
  float rl1 = relp[rb + K4];
  float rl2 = relp[rb + (size_t)W0 * K4];
  float rl3 = relp[rb + (size_t)W0 * K4 + K4];

  // ---- up_idx output: 4 pixels x 32 m per block ----
  if (tid < 128) {
    const int mm = tid & 31, t = tid >> 5;
    const int j2 = mm >> 2, o2 = mm & 3;
    const int pix = (tp[j2 * 2] * 2 + (o2 >> 1)) * W0 + tp[j2 * 2 + 1] * 2 + (o2 & 1);
    const int prow = r0 + (t >> 1), pcol = c0 + (t & 1);
    out_idx[((size_t)b * PIX + prow * W0 + pcol) * K4 + mm] = (float)pix;
  }

  // ---- QK: s[t] = q[t,h,:] . K[m,h,:] ; q loaded direct (broadcast lines) ----
  const half2_t* kh = (const half2_t*)kw4;   // 16 half2
  float acc[4];
#pragma unroll
  for (int t = 0; t < 4; ++t) {
    const int pix = (r0 + (t >> 1)) * W0 + c0 + (t & 1);
    const uint4* qptr = (const uint4*)&qT[((size_t)b * PIX + pix) * C + h * D];
    uint4 qw4[4];
#pragma unroll
    for (int i = 0; i < 4; ++i) qw4[i] = qptr[i];
    const half2_t* qh = (const half2_t*)qw4;  // 16 half2
    float s = 0.f;
#pragma unroll
    for (int i = 0; i < 16; ++i) s = fdot2_acc(qh[i], kh[i], s);
    acc[t] = s;
  }

  const float scale = 0.17677669529663687f;  // 1/sqrt(32)
  float sv[4];
  sv[0] = acc[0] * scale + rl0;
  sv[1] = acc[1] * scale + rl1;
  sv[2] = acc[2] * scale + rl2;
  sv[3] = acc[3] * scale + rl3;

  // ---- softmax over m (32-lane xor shuffles stay inside the m group) ----
  float pr4[4];
#pragma unroll
  for (int t = 0; t < 4; ++t) {
    float x = sv[t];
    float mx = x;
#pragma unroll
    for (int off = 16; off > 0; off >>= 1) mx = fmaxf(mx, __shfl_xor(mx, off));
    float pbit = __expf(x - mx);
    float sm = pbit;
#pragma unroll
    for (int off = 16; off > 0; off >>= 1) sm += __shfl_xor(sm, off);
    pr4[t] = pbit / sm;
  }

  // ---- probs fp16, d-major: dword (d*4+t) of head h = (A[t][2d], A[t][2d+1]) ----
  {
    const int d = m >> 1, lohi = m & 1;
#pragma unroll
    for (int t = 0; t < 4; ++t)
      pph[h * 128 + d * 8 + t * 2 + lohi] = __float2half(pr4[t]);
  }
  __syncthreads();   // (single barrier) V + probs visible

  // ---- PV: out[t,h,j] = sum_m A[t,h,m] * V[m,h,j] via fdot2 over m-pairs ----
  float o0 = 0.f, o1 = 0.f, o2 = 0.f, o3 = 0.f;
  const uint4* pp = (const uint4*)&pph[h * 128];
  const __half* vcol = &vsh[h * D + m];
#pragma unroll
  for (int d = 0; d < 16; ++d) {
    uint4 u = pp[d];                       // broadcast per h-group
    __half vlo = vcol[(2 * d) * VST];
    __half vhi = vcol[(2 * d + 1) * VST];
    __half2 vp2 = __halves2half2(vlo, vhi);    // ds_read_u16 + _d16_hi
    half2_t vp = __builtin_bit_cast(half2_t, vp2);
    o0 = fdot2_acc(__builtin_bit_cast(half2_t, u.x), vp, o0);
    o1 = fdot2_acc(__builtin_bit_cast(half2_t, u.y), vp, o1);
    o2 = fdot2_acc(__builtin_bit_cast(half2_t, u.z), vp, o2);
    o3 = fdot2_acc(__builtin_bit_cast(half2_t, u.w), vp, o3);
  }

  const size_t ob = ((size_t)b * PIX + (size_t)r0 * W0 + c0) * C + h * D + m;
  out_msg[ob] = o0;
  out_msg[ob + C] = o1;
  out_msg[ob + (size_t)W0 * C] = o2;
  out_msg[ob + (size_t)W0 * C + C] = o3;
}

// ---------------------------------------------------------------------------
// Fallback (Round-1 kernel, known correct): used only if ws too small.
// ---------------------------------------------------------------------------
__global__ __launch_bounds__(256) void cascade_attn_fallback(
    const float* __restrict__ query, const float* __restrict__ key,
    const float* __restrict__ value, const int* __restrict__ topk,
    const float* __restrict__ relp, float* __restrict__ out_msg,
    float* __restrict__ out_idx)
{
  __shared__ float kv[K4 * KST];
  __shared__ float qs[4 * C];
  __shared__ float as_[NH * K4 * 4];

  const int tid = threadIdx.x;
  const int bid = blockIdx.x;
  const int b = bid >> 12;
  const int l = bid & (LBLK - 1);
  const int by = l >> 6, bx = l & 63;
  const int r0 = by * 2, c0 = bx * 2;

  const size_t plane = (size_t)PIX;
  const float* qb = query + (size_t)b * C * plane;
  const float* kb = key + (size_t)b * C * plane;
  const float* vb = value + (size_t)b * C * plane;
  const int* tp = topk + ((size_t)b * LBLK + l) * 16;

  {
    const float* qp = qb + (size_t)tid * plane + r0 * W0 + c0;
    float2 a = *(const float2*)qp;
    float2 bb = *(const float2*)(qp + W0);
    qs[0 * C + tid] = a.x; qs[1 * C + tid] = a.y;
    qs[2 * C + tid] = bb.x; qs[3 * C + tid] = bb.y;
  }
#pragma unroll
  for (int it = 0; it < 16; ++it) {
    const int jj = it >> 1, x = it & 1;
    const int pr = tp[jj * 2] * 2 + x;
    const int pc = tp[jj * 2 + 1] * 2;
    float2 f = *(const float2*)(kb + (size_t)tid * plane + pr * W0 + pc);
    const int m0 = jj * 4 + x * 2;
    kv[m0 * KST + tid] = f.x;
    kv[(m0 + 1) * KST + tid] = f.y;
  }
  if (tid < 128) {
    const int m = tid & 31, t = tid >> 5;
    const int jj = m >> 2, o = m & 3;
    const int pix = (tp[jj * 2] * 2 + (o >> 1)) * W0 + tp[jj * 2 + 1] * 2 + (o & 1);
    const int prow = r0 + (t >> 1), pcol = c0 + (t & 1);
    out_idx[((size_t)b * plane + prow * W0 + pcol) * K4 + m] = (float)pix;
  }
  __syncthreads();

  const int h = tid >> 5;
  const int m = tid & 31;
  float a0 = 0.f, a1 = 0.f, a2 = 0.f, a3 = 0.f;
#pragma unroll
  for (int dq = 0; dq < 8; ++dq) {
    const int off = h * D + dq * 4;
    float4 q0 = *(const float4*)&qs[0 * C + off];
    float4 q1 = *(const float4*)&qs[1 * C + off];
    float4 q2 = *(const float4*)&qs[2 * C + off];
    float4 q3 = *(const float4*)&qs[3 * C + off];
    float2 ka = *(const float2*)&kv[m * KST + off];
    float2 kc = *(const float2*)&kv[m * KST + off + 2];
    a0 += q0.x * ka.x + q0.y * ka.y + q0.z * kc.x + q0.w * kc.y;
    a1 += q1.x * ka.x + q1.y * ka.y + q1.z * kc.x + q1.w * kc.y;
    a2 += q2.x * ka.x + q2.y * ka.y + q2.z * kc.x + q2.w * kc.y;
    a3 += q3.x * ka.x + q3.y * ka.y + q3.z * kc.x + q3.w * kc.y;
  }
  const float scale = 0.17677669529663687f;
  const size_t rb = ((((size_t)b * NH + h) * H0 + r0) * W0 + c0) * K4 + m;
  float sv[4];
  sv[0] = a0 * scale + relp[rb];
  sv[1] = a1 * scale + relp[rb + K4];
  sv[2] = a2 * scale + relp[rb + (size_t)W0 * K4];
  sv[3] = a3 * scale + relp[rb + (size_t)W0 * K4 + K4];
  float pr4[4];
#pragma unroll
  for (int t = 0; t < 4; ++t) {
    float x = sv[t];
    float mx = x;
#pragma unroll
    for (int off = 16; off > 0; off >>= 1) mx = fmaxf(mx, __shfl_xor(mx, off));
    float pbit = __expf(x - mx);
    float sm = pbit;
#pragma unroll
    for (int off = 16; off > 0; off >>= 1) sm += __shfl_xor(sm, off);
    pr4[t] = pbit / sm;
  }
  *(float4*)&as_[tid * 4] = make_float4(pr4[0], pr4[1], pr4[2], pr4[3]);
  __syncthreads();
#pragma unroll
  for (int it = 0; it < 16; ++it) {
    const int jj = it >> 1, x = it & 1;
    const int pr = tp[jj * 2] * 2 + x;
    const int pc = tp[jj * 2 + 1] * 2;
    float2 f = *(const float2*)(vb + (size_t)tid * plane + pr * W0 + pc);
    const int m0 = jj * 4 + x * 2;
    kv[m0 * KST + tid] = f.x;
    kv[(m0 + 1) * KST + tid] = f.y;
  }
  __syncthreads();
  float o0 = 0.f, o1 = 0.f, o2 = 0.f, o3 = 0.f;
#pragma unroll
  for (int mm = 0; mm < 32; ++mm) {
    float4 a4 = *(const float4*)&as_[(h * K4 + mm) * 4];
    float vv = kv[mm * KST + h * D + m];
    o0 += a4.x * vv; o1 += a4.y * vv; o2 += a4.z * vv; o3 += a4.w * vv;
  }
  const size_t ob = ((size_t)b * plane + (size_t)r0 * W0 + c0) * C + h * D + m;
  out_msg[ob] = o0;
  out_msg[ob + C] = o1;
  out_msg[ob + (size_t)W0 * C] = o2;
  out_msg[ob + (size_t)W0 * C + C] = o3;
}

extern "C" void kernel_launch(void* const* d_in, const int* in_sizes, int n_in,
                              void* d_out, int out_size, void* d_ws, size_t ws_size,
                              hipStream_t stream) {
  const float* q = (const float*)d_in[0];
  const float* k = (const float*)d_in[1];
  const float* v = (const float*)d_in[2];
  const int* tp = (const int*)d_in[3];
  const float* rp = (const float*)d_in[4];

  float* out_msg = (float*)d_out;
  float* out_idx = out_msg + (size_t)2 * PIX * C;

  const size_t n_elem = (size_t)2 * PIX * C;
  const size_t needed = 3 * n_elem * sizeof(__half);  // 50.3 MB
  if (ws_size >= needed) {
    __half* qT = (__half*)d_ws;
    __half* kT = qT + n_elem;
    __half* vT = kT + n_elem;
    dim3 tg(PIX / 64, C / 64, 6);
    hipLaunchKernelGGL(transpose_qkv_kernel, tg, dim3(256), 0, stream,
                       q, k, v, qT, kT, vT);
    hipLaunchKernelGGL(cascade_attn_f16, dim3(2 * LBLK), dim3(256), 0, stream,
                       qT, kT, vT, tp, rp, out_msg, out_idx);
  } else {
    hipLaunchKernelGGL(cascade_attn_fallback, dim3(2 * LBLK), dim3(256), 0, stream,
                       q, k, v, tp, rp, out_msg, out_idx);
  }
}

// Round 6
// 201.398 us; speedup vs baseline: 1.2341x; 1.1539x over previous
//
#include <hip/hip_runtime.h>
#include <hip/hip_fp16.h>
#include <math.h>

// Problem constants (fixed by the reference setup_inputs)
constexpr int NH = 8;     // heads
constexpr int D = 32;     // head dim (c/nh)
constexpr int C = 256;    // channels
constexpr int H0 = 128;
constexpr int W0 = 128;
constexpr int PIX = H0 * W0;   // 16384
constexpr int LBLK = 4096;     // (H0/2)*(W0/2)
constexpr int K4 = 32;         // 4*k candidates
constexpr int KSTH = 260;      // K/V LDS row stride in halves (520 B -> <=2-way banks)
constexpr int KST = 258;       // fp32 fallback stride

typedef _Float16 half2_t __attribute__((ext_vector_type(2)));

#if defined(__has_builtin)
#if __has_builtin(__builtin_amdgcn_fdot2)
#define HAVE_FDOT2 1
#endif
#endif

__device__ __forceinline__ float fdot2_acc(half2_t a, half2_t b, float c) {
#ifdef HAVE_FDOT2
  return __builtin_amdgcn_fdot2(a, b, c, false);
#else
  return c + (float)a.x * (float)b.x + (float)a.y * (float)b.y;
#endif
}

// ---------------------------------------------------------------------------
// Pass 1: transpose q/k/v [b, C, PIX] -> fp16 [b, PIX, C] in workspace.
// grid = (PIX/64, C/64, 6)  z: 0,1=q(b) 2,3=k(b) 4,5=v(b)
// ---------------------------------------------------------------------------
__global__ __launch_bounds__(256) void transpose_qkv_kernel(
    const float* __restrict__ q, const float* __restrict__ k,
    const float* __restrict__ v, __half* __restrict__ qT,
    __half* __restrict__ kT, __half* __restrict__ vT)
{
  __shared__ float tile[64 * 65];
  const int z = blockIdx.z;
  const int b = z & 1;
  const int arr = z >> 1;   // 0=q, 1=k, 2=v
  const float* src = (arr == 0 ? q : arr == 1 ? k : v) + (size_t)b * C * PIX;
  __half* dst = (arr == 0 ? qT : arr == 1 ? kT : vT) + (size_t)b * PIX * C;

  const int p0 = blockIdx.x * 64;
  const int c0 = blockIdx.y * 64;
  const int t15 = threadIdx.x & 15;
  const int thi4 = threadIdx.x >> 4;   // 0..15

#pragma unroll
  for (int r = 0; r < 4; ++r) {
    const int ch = thi4 + r * 16;      // channel row
    const int p4 = t15 * 4;            // pixel start
    float4 f = *(const float4*)&src[(size_t)(c0 + ch) * PIX + p0 + p4];
    tile[(p4 + 0) * 65 + ch] = f.x;
    tile[(p4 + 1) * 65 + ch] = f.y;
    tile[(p4 + 2) * 65 + ch] = f.z;
    tile[(p4 + 3) * 65 + ch] = f.w;
  }
  __syncthreads();

  const int t7 = threadIdx.x & 7;
  const int th8 = threadIdx.x >> 3;  // 0..31
#pragma unroll
  for (int r = 0; r < 2; ++r) {
    const int p = th8 + r * 32;
    const int c8 = t7 * 8;
    const float* tr = &tile[p * 65 + c8];
    __half2 h0 = __floats2half2_rn(tr[0], tr[1]);
    __half2 h1 = __floats2half2_rn(tr[2], tr[3]);
    __half2 h2 = __floats2half2_rn(tr[4], tr[5]);
    __half2 h3 = __floats2half2_rn(tr[6], tr[7]);
    uint4 u;
    u.x = *(unsigned*)&h0; u.y = *(unsigned*)&h1;
    u.z = *(unsigned*)&h2; u.w = *(unsigned*)&h3;
    *(uint4*)&dst[(size_t)(p0 + p) * C + c0 + c8] = u;   // 16B aligned
  }
}

// ---------------------------------------------------------------------------
// Pass 2: attention. One block per (b, l). All of q/K/V fp16 from ws.
// Baseline (51 us) skeleton restored verbatim: q+K staged to LDS, V
// prefetched to regs, QK via v_dot2_f32_f16, probs overlaid on dead q buf,
// V overlaid on dead K buf.  ONLY change vs baseline (R5-verified-correct):
//  - probs stored d-major fp16 [h][d*8 + t*2 + lohi] -> PV reads 16 b128
//    broadcasts (was 32 b64)
//  - PV inner loop pairs V rows (2d, 2d+1) into half2 and uses fdot2
//    (removes ~200 VALU unpack/FMA per lane)
// LDS: kvh 16,640 B + qph 2,048 B = 18,688 B -> 8 blocks/CU.
// ---------------------------------------------------------------------------
__global__ __launch_bounds__(256) void cascade_attn_f16(
    const __half* __restrict__ qT,     // [2, PIX, C] fp16
    const __half* __restrict__ kT,
    const __half* __restrict__ vT,
    const int* __restrict__ topk,      // [2,4096,8,2] int32
    const float* __restrict__ relp,    // [2,8,128,128,32] fp32
    float* __restrict__ out_msg,       // [2,16384,256]
    float* __restrict__ out_idx)       // [2,16384,32] (float values)
{
  __shared__ __half kvh[K4 * KSTH];   // gathered K, then V (16,640 B)
  __shared__ __half qph[4 * C];       // q fp16 [t][c]; after QK: probs d-major

  const int tid = threadIdx.x;
  const int bid = blockIdx.x;
  const int b = bid >> 12;
  const int l = bid & (LBLK - 1);
  const int by = l >> 6, bx = l & 63;
  const int r0 = by * 2, c0 = bx * 2;

  const int* tp = topk + ((size_t)b * LBLK + l) * 16;

  const int h = tid >> 5;   // head
  const int m = tid & 31;   // candidate (QK) / head-dim lane j (PV)

  // ---- stage q: 4 pixels x 256 contiguous halves; 1 uint2 (4 halves)/thread ----
  {
    const int t = tid >> 6, ln = tid & 63;
    const int pix = r0 * W0 + c0 + (t >> 1) * W0 + (t & 1);
    uint2 f = *(const uint2*)&qT[((size_t)b * PIX + pix) * C + ln * 4];
    *(uint2*)&qph[t * C + ln * 4] = f;
  }

  // ---- candidate pixel for this thread's cooperative gather slice ----
  const int p = tid >> 3;        // candidate 0..31
  const int ln8 = tid & 7;
  const int jj = p >> 2, po = p & 3;
  const int gpix = (tp[jj * 2] * 2 + (po >> 1)) * W0 + tp[jj * 2 + 1] * 2 + (po & 1);

  // ---- stage gathered K: 4 x uint4 (8 halves each) per thread ----
  {
    const __half* src = &kT[((size_t)b * PIX + gpix) * C + ln8 * 8];
#pragma unroll
    for (int i = 0; i < 4; ++i) {
      uint4 f = *(const uint4*)(src + i * 64);      // 16B aligned
      __half* dst = &kvh[p * KSTH + ln8 * 8 + i * 64];
      *(uint2*)dst = make_uint2(f.x, f.y);          // 8B aligned (row = 520 B)
      *(uint2*)(dst + 4) = make_uint2(f.z, f.w);
    }
  }

  // ---- prefetch gathered V into registers (latency hides behind QK) ----
  uint4 vreg[4];
  {
    const __half* src = &vT[((size_t)b * PIX + gpix) * C + ln8 * 8];
#pragma unroll
    for (int i = 0; i < 4; ++i) vreg[i] = *(const uint4*)(src + i * 64);
  }

  // ---- prefetch rel_pos for this (h,m): 4 floats, coalesced over m ----
  const size_t rb = ((((size_t)b * NH + h) * H0 + r0) * W0 + c0) * K4 + m;
  float rl0 = relp[rb];
  float rl1 = relp[rb + K4];
  float rl2 = relp[rb + (size_t)W0 * K4];
  float rl3 = relp[rb + (size_t)W0 * K4 + K4];

  // ---- up_idx output: 4 pixels x 32 m per block ----
  if (tid < 128) {
    const int mm = tid & 31, t = tid >> 5;
    const int j2 = mm >> 2, o2 = mm & 3;
    const int pix = (tp[j2 * 2] * 2 + (o2 >> 1)) * W0 + tp[j2 * 2 + 1] * 2 + (o2 & 1);
    const int prow = r0 + (t >> 1), pcol = c0 + (t & 1);
    out_idx[((size_t)b * PIX + prow * W0 + pcol) * K4 + mm] = (float)pix;
  }
  __syncthreads();   // (1) q + K staged

  // ---- load K fragment from LDS: K[m][h*32..+31] as 16 half2 ----
  uint2 kw[8];
  {
    const __half* kbase = &kvh[m * KSTH + h * D];   // 8B aligned
#pragma unroll
    for (int i = 0; i < 8; ++i) kw[i] = *(const uint2*)(kbase + i * 4);
  }
  const half2_t* kh = (const half2_t*)kw;           // 16 half2

  // ---- QK via fdot2: s[t] = q[t,h,:] . K[m,h,:] ----
  float acc[4] = {0.f, 0.f, 0.f, 0.f};
#pragma unroll
  for (int t = 0; t < 4; ++t) {
    uint4 qw[2];
    const uint4* qf = (const uint4*)&qph[t * C + h * D];  // 16B aligned, broadcast
    qw[0] = qf[0];
    qw[1] = qf[1];
    const half2_t* qh2 = (const half2_t*)qw;        // 8 half2
    uint4 qw2[2];
    qw2[0] = qf[2];
    qw2[1] = qf[3];
    const half2_t* qh2b = (const half2_t*)qw2;      // 8 half2
#pragma unroll
    for (int i = 0; i < 8; ++i) acc[t] = fdot2_acc(qh2[i], kh[i], acc[t]);
#pragma unroll
    for (int i = 0; i < 8; ++i) acc[t] = fdot2_acc(qh2b[i], kh[8 + i], acc[t]);
  }

  const float scale = 0.17677669529663687f;  // 1/sqrt(32)
  float sv[4];
  sv[0] = acc[0] * scale + rl0;
  sv[1] = acc[1] * scale + rl1;
  sv[2] = acc[2] * scale + rl2;
  sv[3] = acc[3] * scale + rl3;

  // ---- softmax over m (32-lane xor shuffles stay inside the m group) ----
  float pr4[4];
#pragma unroll
  for (int t = 0; t < 4; ++t) {
    float x = sv[t];
    float mx = x;
#pragma unroll
    for (int off = 16; off > 0; off >>= 1) mx = fmaxf(mx, __shfl_xor(mx, off));
    float pbit = __expf(x - mx);
    float sm = pbit;
#pragma unroll
    for (int off = 16; off > 0; off >>= 1) sm += __shfl_xor(sm, off);
    pr4[t] = pbit / sm;
  }
  __syncthreads();   // (2) all QK reads of qph & kvh complete

  // ---- write probs fp16 into qph (q dead), d-major:
  //      half index h*128 + (m>>1)*8 + t*2 + (m&1)
  //      -> dword (d*4+t) of head h = (A[t][2d], A[t][2d+1])  [R5-verified] ----
  {
    const int d = m >> 1, lohi = m & 1;
#pragma unroll
    for (int t = 0; t < 4; ++t)
      qph[h * 128 + d * 8 + t * 2 + lohi] = __float2half(pr4[t]);
  }
  // ---- write V into kvh (K dead), baseline row layout ----
#pragma unroll
  for (int i = 0; i < 4; ++i) {
    __half* dst = &kvh[p * KSTH + ln8 * 8 + i * 64];
    *(uint2*)dst = make_uint2(vreg[i].x, vreg[i].y);
    *(uint2*)(dst + 4) = make_uint2(vreg[i].z, vreg[i].w);
  }
  __syncthreads();   // (3) probs + V visible

  // ---- PV: out[t,h,j] = sum_m A[t,h,m] * V[m,h,j] via fdot2 over m-pairs
  //      [R5-verified math; only LDS stride differs: KSTH rows] ----
  float o0 = 0.f, o1 = 0.f, o2 = 0.f, o3 = 0.f;
  const uint4* pp = (const uint4*)&qph[h * 128];
  const __half* vcol = &kvh[h * D + m];
#pragma unroll
  for (int d = 0; d < 16; ++d) {
    uint4 u = pp[d];                       // broadcast per h-group
    __half vlo = vcol[(2 * d) * KSTH];
    __half vhi = vcol[(2 * d + 1) * KSTH];
    __half2 vp2 = __halves2half2(vlo, vhi);    // ds_read_u16 + _d16_hi
    half2_t vp = __builtin_bit_cast(half2_t, vp2);
    o0 = fdot2_acc(__builtin_bit_cast(half2_t, u.x), vp, o0);
    o1 = fdot2_acc(__builtin_bit_cast(half2_t, u.y), vp, o1);
    o2 = fdot2_acc(__builtin_bit_cast(half2_t, u.z), vp, o2);
    o3 = fdot2_acc(__builtin_bit_cast(half2_t, u.w), vp, o3);
  }

  const size_t ob = ((size_t)b * PIX + (size_t)r0 * W0 + c0) * C + h * D + m;
  out_msg[ob] = o0;
  out_msg[ob + C] = o1;
  out_msg[ob + (size_t)W0 * C] = o2;
  out_msg[ob + (size_t)W0 * C + C] = o3;
}

// ---------------------------------------------------------------------------
// Fallback (Round-1 kernel, known correct): used only if ws too small.
// ---------------------------------------------------------------------------
__global__ __launch_bounds__(256) void cascade_attn_fallback(
    const float* __restrict__ query, const float* __restrict__ key,
    const float* __restrict__ value, const int* __restrict__ topk,
    const float* __restrict__ relp, float* __restrict__ out_msg,
    float* __restrict__ out_idx)
{
  __shared__ float kv[K4 * KST];
  __shared__ float qs[4 * C];
  __shared__ float as_[NH * K4 * 4];

  const int tid = threadIdx.x;
  const int bid = blockIdx.x;
  const int b = bid >> 12;
  const int l = bid & (LBLK - 1);
  const int by = l >> 6, bx = l & 63;
  const int r0 = by * 2, c0 = bx * 2;

  const size_t plane = (size_t)PIX;
  const float* qb = query + (size_t)b * C * plane;
  const float* kb = key + (size_t)b * C * plane;
  const float* vb = value + (size_t)b * C * plane;
  const int* tp = topk + ((size_t)b * LBLK + l) * 16;

  {
    const float* qp = qb + (size_t)tid * plane + r0 * W0 + c0;
    float2 a = *(const float2*)qp;
    float2 bb = *(const float2*)(qp + W0);
    qs[0 * C + tid] = a.x; qs[1 * C + tid] = a.y;
    qs[2 * C + tid] = bb.x; qs[3 * C + tid] = bb.y;
  }
#pragma unroll
  for (int it = 0; it < 16; ++it) {
    const int jj = it >> 1, x = it & 1;
    const int pr = tp[jj * 2] * 2 + x;
    const int pc = tp[jj * 2 + 1] * 2;
    float2 f = *(const float2*)(kb + (size_t)tid * plane + pr * W0 + pc);
    const int m0 = jj * 4 + x * 2;
    kv[m0 * KST + tid] = f.x;
    kv[(m0 + 1) * KST + tid] = f.y;
  }
  if (tid < 128) {
    const int m = tid & 31, t = tid >> 5;
    const int jj = m >> 2, o = m & 3;
    const int pix = (tp[jj * 2] * 2 + (o >> 1)) * W0 + tp[jj * 2 + 1] * 2 + (o & 1);
    const int prow = r0 + (t >> 1), pcol = c0 + (t & 1);
    out_idx[((size_t)b * plane + prow * W0 + pcol) * K4 + m] = (float)pix;
  }
  __syncthreads();

  const int h = tid >> 5;
  const int m = tid & 31;
  float a0 = 0.f, a1 = 0.f, a2 = 0.f, a3 = 0.f;
#pragma unroll
  for (int dq = 0; dq < 8; ++dq) {
    const int off = h * D + dq * 4;
    float4 q0 = *(const float4*)&qs[0 * C + off];
    float4 q1 = *(const float4*)&qs[1 * C + off];
    float4 q2 = *(const float4*)&qs[2 * C + off];
    float4 q3 = *(const float4*)&qs[3 * C + off];
    float2 ka = *(const float2*)&kv[m * KST + off];
    float2 kc = *(const float2*)&kv[m * KST + off + 2];
    a0 += q0.x * ka.x + q0.y * ka.y + q0.z * kc.x + q0.w * kc.y;
    a1 += q1.x * ka.x + q1.y * ka.y + q1.z * kc.x + q1.w * kc.y;
    a2 += q2.x * ka.x + q2.y * ka.y + q2.z * kc.x + q2.w * kc.y;
    a3 += q3.x * ka.x + q3.y * ka.y + q3.z * kc.x + q3.w * kc.y;
  }
  const float scale = 0.17677669529663687f;
  const size_t rb = ((((size_t)b * NH + h) * H0 + r0) * W0 + c0) * K4 + m;
  float sv[4];
  sv[0] = a0 * scale + relp[rb];
  sv[1] = a1 * scale + relp[rb + K4];
  sv[2] = a2 * scale + relp[rb + (size_t)W0 * K4];
  sv[3] = a3 * scale + relp[rb + (size_t)W0 * K4 + K4];
  float pr4[4];
#pragma unroll
  for (int t = 0; t < 4; ++t) {
    float x = sv[t];
    float mx = x;
#pragma unroll
    for (int off = 16; off > 0; off >>= 1) mx = fmaxf(mx, __shfl_xor(mx, off));
    float pbit = __expf(x - mx);
    float sm = pbit;
#pragma unroll
    for (int off = 16; off > 0; off >>= 1) sm += __shfl_xor(sm, off);
    pr4[t] = pbit / sm;
  }
  *(float4*)&as_[tid * 4] = make_float4(pr4[0], pr4[1], pr4[2], pr4[3]);
  __syncthreads();
#pragma unroll
  for (int it = 0; it < 16; ++it) {
    const int jj = it >> 1, x = it & 1;
    const int pr = tp[jj * 2] * 2 + x;
    const int pc = tp[jj * 2 + 1] * 2;
    float2 f = *(const float2*)(vb + (size_t)tid * plane + pr * W0 + pc);
    const int m0 = jj * 4 + x * 2;
    kv[m0 * KST + tid] = f.x;
    kv[(m0 + 1) * KST + tid] = f.y;
  }
  __syncthreads();
  float o0 = 0.f, o1 = 0.f, o2 = 0.f, o3 = 0.f;
#pragma unroll
  for (int mm = 0; mm < 32; ++mm) {
    float4 a4 = *(const float4*)&as_[(h * K4 + mm) * 4];
    float vv = kv[mm * KST + h * D + m];
    o0 += a4.x * vv; o1 += a4.y * vv; o2 += a4.z * vv; o3 += a4.w * vv;
  }
  const size_t ob = ((size_t)b * plane + (size_t)r0 * W0 + c0) * C + h * D + m;
  out_msg[ob] = o0;
  out_msg[ob + C] = o1;
  out_msg[ob + (size_t)W0 * C] = o2;
  out_msg[ob + (size_t)W0 * C + C] = o3;
}

extern "C" void kernel_launch(void* const* d_in, const int* in_sizes, int n_in,
                              void* d_out, int out_size, void* d_ws, size_t ws_size,
                              hipStream_t stream) {
  const float* q = (const float*)d_in[0];
  const float* k = (const float*)d_in[1];
  const float* v = (const float*)d_in[2];
  const int* tp = (const int*)d_in[3];
  const float* rp = (const float*)d_in[4];

  float* out_msg = (float*)d_out;
  float* out_idx = out_msg + (size_t)2 * PIX * C;

  const size_t n_elem = (size_t)2 * PIX * C;
  const size_t needed = 3 * n_elem * sizeof(__half);  // 50.3 MB
  if (ws_size >= needed) {
    __half* qT = (__half*)d_ws;
    __half* kT = qT + n_elem;
    __half* vT = kT + n_elem;
    dim3 tg(PIX / 64, C / 64, 6);
    hipLaunchKernelGGL(transpose_qkv_kernel, tg, dim3(256), 0, stream,
                       q, k, v, qT, kT, vT);
    hipLaunchKernelGGL(cascade_attn_f16, dim3(2 * LBLK), dim3(256), 0, stream,
                       qT, kT, vT, tp, rp, out_msg, out_idx);
  } else {
    hipLaunchKernelGGL(cascade_attn_fallback, dim3(2 * LBLK), dim3(256), 0, stream,
                       q, k, v, tp, rp, out_msg, out_idx);
  }
}